// Round 1
// 422.490 us; speedup vs baseline: 1.4245x; 1.4245x over previous
//
#include <hip/hip_runtime.h>
#include <math.h>

#define N_NODES 100000
#define N_EDGES 1600000
#define D_IN 64
#define D_HID 64
#define D_OUT 16

// ================= CSR build (by dst) =================

__global__ void k_zero(int* __restrict__ cnt, int n) {
    int i = blockIdx.x * blockDim.x + threadIdx.x;
    if (i < n) cnt[i] = 0;
}

__global__ void k_count(const int* __restrict__ dst, int* __restrict__ cnt, int e) {
    int i = blockIdx.x * blockDim.x + threadIdx.x;
    if (i < e) atomicAdd(&cnt[dst[i]], 1);
}

__global__ void k_dinv(const int* __restrict__ cnt, float* __restrict__ dinv, int n) {
    int i = blockIdx.x * blockDim.x + threadIdx.x;
    if (i < n) dinv[i] = rsqrtf((float)cnt[i] + 1.0f);  // +1 self-loop
}

// scanA: per-block exclusive scan of 1024 ints (4/thread); block totals -> bsums
__global__ void k_scanA(const int* __restrict__ cnt, int* __restrict__ off,
                        int* __restrict__ bsums, int n) {
    __shared__ int sd[256];
    int t = threadIdx.x;
    int base = blockIdx.x * 1024 + t * 4;
    int e0 = (base + 0 < n) ? cnt[base + 0] : 0;
    int e1 = (base + 1 < n) ? cnt[base + 1] : 0;
    int e2 = (base + 2 < n) ? cnt[base + 2] : 0;
    int e3 = (base + 3 < n) ? cnt[base + 3] : 0;
    int s = e0 + e1 + e2 + e3;
    sd[t] = s;
    __syncthreads();
    for (int o = 1; o < 256; o <<= 1) {
        int v = (t >= o) ? sd[t - o] : 0;
        __syncthreads();
        sd[t] += v;
        __syncthreads();
    }
    int excl = sd[t] - s;
    if (base + 0 < n) off[base + 0] = excl;
    if (base + 1 < n) off[base + 1] = excl + e0;
    if (base + 2 < n) off[base + 2] = excl + e0 + e1;
    if (base + 3 < n) off[base + 3] = excl + e0 + e1 + e2;
    if (t == 0) bsums[blockIdx.x] = sd[255];
}

// scanB: exclusive scan of nb (<=128) block sums; off[n] = total (=E)
__global__ void k_scanB(int* __restrict__ bsums, int* __restrict__ off, int nb, int n) {
    __shared__ int sd[128];
    int t = threadIdx.x;
    int v = (t < nb) ? bsums[t] : 0;
    sd[t] = v;
    __syncthreads();
    for (int o = 1; o < 128; o <<= 1) {
        int u = (t >= o) ? sd[t - o] : 0;
        __syncthreads();
        sd[t] += u;
        __syncthreads();
    }
    if (t < nb) bsums[t] = sd[t] - v;
    if (t == 127) off[n] = sd[127];
}

__global__ void k_scanC(int* __restrict__ off, int* __restrict__ cursor,
                        const int* __restrict__ bsums, int n) {
    int i = blockIdx.x * blockDim.x + threadIdx.x;
    if (i < n) {
        int v = off[i] + bsums[i >> 10];
        off[i] = v;
        cursor[i] = v;
    }
}

__global__ void k_fill(const int* __restrict__ src, const int* __restrict__ dst,
                       int* __restrict__ cursor, int* __restrict__ csr, int e) {
    int i = blockIdx.x * blockDim.x + threadIdx.x;
    if (i < e) {
        int d = dst[i];
        int pos = atomicAdd(&cursor[d], 1);
        csr[pos] = src[i];
    }
}

// ================= GEMM1: h1 = x @ W1 =================
// 256 threads = 4 rows x 64 cols; W1 (64x64) in LDS.

__global__ void k_gemm1(const float* __restrict__ x, const float* __restrict__ W,
                        float* __restrict__ h, int n) {
    __shared__ float Ws[64 * 64];
    __shared__ float xs[4][64];
    int tid = threadIdx.x;
    for (int i = tid; i < 64 * 64; i += 256) Ws[i] = W[i];
    int r = tid >> 6;
    int c = tid & 63;
    int row = blockIdx.x * 4 + r;
    if (row < n) xs[r][c] = x[(size_t)row * 64 + c];
    __syncthreads();
    if (row < n) {
        float acc = 0.0f;
#pragma unroll
        for (int k = 0; k < 64; ++k) acc = fmaf(xs[r][k], Ws[k * 64 + c], acc);
        h[(size_t)row * 64 + c] = acc;
    }
}

// ======== Layer-1 aggregation (gather, no atomics) fused with relu+b1 and GEMM2 ========
// 4 waves/block, one node per wave; lane = feature.
// out1[d,f] = dinv[d] * ( h1[d,f]*dinv[d] + sum_j h1[src_j,f]*dinv[src_j] )
// then v = relu(out1 + b1); h2[d] = v @ W2 via LDS transpose + shfl reduce.

__global__ void k_agg1_gemm2(const float* __restrict__ h1, const int* __restrict__ off,
                             const int* __restrict__ csr, const float* __restrict__ dinv,
                             const float* __restrict__ W2, const float* __restrict__ b1,
                             float* __restrict__ h2, int n) {
    __shared__ float W2s[64 * 16];
    __shared__ float xs[4][64];
    int tid = threadIdx.x;
    for (int i = tid; i < 64 * 16; i += 256) W2s[i] = W2[i];
    int w = tid >> 6;   // wave = node within block
    int f = tid & 63;   // feature
    int d = blockIdx.x * 4 + w;
    if (d < n) {
        float dd = dinv[d];
        float acc0 = h1[(size_t)d * 64 + f] * dd;  // self-loop term (dd factored out)
        float acc1 = 0.0f;
        int j = off[d], je = off[d + 1];
        for (; j + 1 < je; j += 2) {
            int s0 = csr[j], s1 = csr[j + 1];
            acc0 = fmaf(h1[(size_t)s0 * 64 + f], dinv[s0], acc0);
            acc1 = fmaf(h1[(size_t)s1 * 64 + f], dinv[s1], acc1);
        }
        if (j < je) {
            int s0 = csr[j];
            acc0 = fmaf(h1[(size_t)s0 * 64 + f], dinv[s0], acc0);
        }
        float v = fmaxf((acc0 + acc1) * dd + b1[f], 0.0f);
        xs[w][f] = v;
    }
    __syncthreads();  // also covers W2s staging
    // GEMM2 part: each wave computes its node's 16 outputs; lane = 16*q + c.
    int q = (tid >> 4) & 3;
    int c = tid & 15;
    float p = 0.0f;
#pragma unroll
    for (int kk = 0; kk < 16; ++kk) {
        int k = q * 16 + kk;
        p = fmaf(xs[w][k], W2s[k * 16 + c], p);
    }
    p += __shfl_xor(p, 16);
    p += __shfl_xor(p, 32);
    if (q == 0 && d < n) h2[(size_t)d * 16 + c] = p;
}

// ======== Layer-2 aggregation fused with b2 + log_softmax ========
// 4 waves/block, one node per wave; lane = 16*q + c. q strides edges, c = feature.

__global__ void k_agg2_lsm(const float* __restrict__ h2, const int* __restrict__ off,
                           const int* __restrict__ csr, const float* __restrict__ dinv,
                           const float* __restrict__ b2, float* __restrict__ y, int n) {
    int tid = threadIdx.x;
    int w = tid >> 6;
    int lane = tid & 63;
    int q = lane >> 4;
    int c = lane & 15;
    int d = blockIdx.x * 4 + w;
    if (d >= n) return;
    float dd = dinv[d];
    float acc = (q == 0) ? h2[(size_t)d * 16 + c] * dd : 0.0f;  // self-loop term
    int jb = off[d], je = off[d + 1];
    for (int j = jb + q; j < je; j += 4) {
        int s = csr[j];
        acc = fmaf(h2[(size_t)s * 16 + c], dinv[s], acc);
    }
    acc += __shfl_xor(acc, 16);
    acc += __shfl_xor(acc, 32);
    float v = acc * dd + b2[c];
    // log_softmax across the 16 features (replicated in each q group)
    float m = v;
#pragma unroll
    for (int o = 1; o < 16; o <<= 1) m = fmaxf(m, __shfl_xor(m, o));
    float ssum = expf(v - m);
#pragma unroll
    for (int o = 1; o < 16; o <<= 1) ssum += __shfl_xor(ssum, o);
    float r = v - (logf(ssum) + m);
    if (q == 0) y[(size_t)d * 16 + c] = r;
}

// ================= launcher =================

extern "C" void kernel_launch(void* const* d_in, const int* in_sizes, int n_in,
                              void* d_out, int out_size, void* d_ws, size_t ws_size,
                              hipStream_t stream) {
    const float* x  = (const float*)d_in[0];
    const int*   ei = (const int*)d_in[1];          // [2, E] row-major
    const float* W1 = (const float*)d_in[2];
    const float* b1 = (const float*)d_in[3];
    const float* W2 = (const float*)d_in[4];
    const float* b2 = (const float*)d_in[5];
    float* y = (float*)d_out;

    const int n = N_NODES;
    const int e = N_EDGES;
    const int* src = ei;
    const int* dst = ei + e;

    // workspace layout (4-byte units); total ~40 MB
    float* ws = (float*)d_ws;
    int*   cnt    = (int*)ws;                       // n
    float* dinv   = ws + 102400;                    // n
    int*   off    = (int*)(ws + 204800);            // n+1
    int*   cursor = (int*)(ws + 307200);            // n
    int*   bsums  = (int*)(ws + 409600);            // <=1024
    float* h1     = ws + 410624;                    // n*64
    int*   csr    = (int*)(h1 + (size_t)n * 64);    // e
    float* h2     = (float*)(csr + e);              // n*16

    const int nb = (n + 1023) / 1024;               // 98 scan blocks (<=128)

    k_zero <<<(n + 255) / 256, 256, 0, stream>>>(cnt, n);
    k_count<<<(e + 255) / 256, 256, 0, stream>>>(dst, cnt, e);
    k_dinv <<<(n + 255) / 256, 256, 0, stream>>>(cnt, dinv, n);
    k_scanA<<<nb, 256, 0, stream>>>(cnt, off, bsums, n);
    k_scanB<<<1, 128, 0, stream>>>(bsums, off, nb, n);
    k_scanC<<<(n + 255) / 256, 256, 0, stream>>>(off, cursor, bsums, n);
    k_fill <<<(e + 255) / 256, 256, 0, stream>>>(src, dst, cursor, csr, e);

    k_gemm1<<<(n + 3) / 4, 256, 0, stream>>>(x, W1, h1, n);
    k_agg1_gemm2<<<(n + 3) / 4, 256, 0, stream>>>(h1, off, csr, dinv, W2, b1, h2, n);
    k_agg2_lsm  <<<(n + 3) / 4, 256, 0, stream>>>(h2, off, csr, dinv, b2, y, n);
}

// Round 2
// 379.847 us; speedup vs baseline: 1.5844x; 1.1123x over previous
//
#include <hip/hip_runtime.h>
#include <math.h>

#define N_NODES 100000
#define N_EDGES 1600000
#define D_IN 64
#define D_HID 64
#define D_OUT 16

// ================= CSR build (by dst) =================

__global__ void k_zero(int* __restrict__ cnt, int n) {
    int i = blockIdx.x * blockDim.x + threadIdx.x;
    if (i < n) cnt[i] = 0;
}

__global__ void k_count(const int* __restrict__ dst, int* __restrict__ cnt, int e) {
    int i = blockIdx.x * blockDim.x + threadIdx.x;
    if (i < e) atomicAdd(&cnt[dst[i]], 1);
}

// scanA: per-block exclusive scan of 1024 ints (4/thread); block totals -> bsums.
// Also computes dinv = rsqrt(deg+1) (fused former k_dinv).
__global__ void k_scanA(const int* __restrict__ cnt, int* __restrict__ off,
                        int* __restrict__ bsums, float* __restrict__ dinv, int n) {
    __shared__ int sd[256];
    int t = threadIdx.x;
    int base = blockIdx.x * 1024 + t * 4;
    int e0 = (base + 0 < n) ? cnt[base + 0] : 0;
    int e1 = (base + 1 < n) ? cnt[base + 1] : 0;
    int e2 = (base + 2 < n) ? cnt[base + 2] : 0;
    int e3 = (base + 3 < n) ? cnt[base + 3] : 0;
    if (base + 0 < n) dinv[base + 0] = rsqrtf((float)e0 + 1.0f);
    if (base + 1 < n) dinv[base + 1] = rsqrtf((float)e1 + 1.0f);
    if (base + 2 < n) dinv[base + 2] = rsqrtf((float)e2 + 1.0f);
    if (base + 3 < n) dinv[base + 3] = rsqrtf((float)e3 + 1.0f);
    int s = e0 + e1 + e2 + e3;
    sd[t] = s;
    __syncthreads();
    for (int o = 1; o < 256; o <<= 1) {
        int v = (t >= o) ? sd[t - o] : 0;
        __syncthreads();
        sd[t] += v;
        __syncthreads();
    }
    int excl = sd[t] - s;
    if (base + 0 < n) off[base + 0] = excl;
    if (base + 1 < n) off[base + 1] = excl + e0;
    if (base + 2 < n) off[base + 2] = excl + e0 + e1;
    if (base + 3 < n) off[base + 3] = excl + e0 + e1 + e2;
    if (t == 0) bsums[blockIdx.x] = sd[255];
}

// scanB: exclusive scan of nb (<=128) block sums; off[n] = total (=E)
__global__ void k_scanB(int* __restrict__ bsums, int* __restrict__ off, int nb, int n) {
    __shared__ int sd[128];
    int t = threadIdx.x;
    int v = (t < nb) ? bsums[t] : 0;
    sd[t] = v;
    __syncthreads();
    for (int o = 1; o < 128; o <<= 1) {
        int u = (t >= o) ? sd[t - o] : 0;
        __syncthreads();
        sd[t] += u;
        __syncthreads();
    }
    if (t < nb) bsums[t] = sd[t] - v;
    if (t == 127) off[n] = sd[127];
}

__global__ void k_scanC(int* __restrict__ off, int* __restrict__ cursor,
                        const int* __restrict__ bsums, int n) {
    int i = blockIdx.x * blockDim.x + threadIdx.x;
    if (i < n) {
        int v = off[i] + bsums[i >> 10];
        off[i] = v;
        cursor[i] = v;
    }
}

__global__ void k_fill(const int* __restrict__ src, const int* __restrict__ dst,
                       int* __restrict__ cursor, int* __restrict__ csr, int e) {
    int i = blockIdx.x * blockDim.x + threadIdx.x;
    if (i < e) {
        int d = dst[i];
        int pos = atomicAdd(&cursor[d], 1);
        csr[pos] = src[i];
    }
}

// ======== Layer 1+2 front half, fully fused ========
// out1 = (A_hat X) W1 + b1  (linearity: aggregate x first, then W1)
// 4 waves/block, one node per wave; lane = feature.
// Phase A: agg[f] = dd*( x[d,f]*dd + sum_j x[src_j,f]*dinv[src_j] )   (4-way unrolled gather)
// Phase B: out1 = agg @ W1 + b1 ; v = relu(out1)       (W1 in LDS)
// Phase C: h2 = v @ W2                                  (W2 in LDS, shfl reduce)

__global__ void k_agg1_fused(const float* __restrict__ x, const int* __restrict__ off,
                             const int* __restrict__ csr, const float* __restrict__ dinv,
                             const float* __restrict__ W1, const float* __restrict__ W2,
                             const float* __restrict__ b1,
                             float* __restrict__ h2, int n) {
    __shared__ float W1s[64 * 64];
    __shared__ float W2s[64 * 16];
    __shared__ float xs[4][64];
    __shared__ float vs[4][64];
    int tid = threadIdx.x;
    for (int i = tid; i < 64 * 64; i += 256) W1s[i] = W1[i];
    for (int i = tid; i < 64 * 16; i += 256) W2s[i] = W2[i];
    int w = tid >> 6;   // wave = node within block
    int f = tid & 63;   // feature
    int d = blockIdx.x * 4 + w;
    if (d < n) {
        float dd = dinv[d];
        float a0 = x[(size_t)d * 64 + f] * dd;  // self-loop term (dd factored out)
        float a1 = 0.0f, a2 = 0.0f, a3 = 0.0f;
        int j = off[d], je = off[d + 1];
        for (; j + 3 < je; j += 4) {
            int s0 = csr[j], s1 = csr[j + 1], s2 = csr[j + 2], s3 = csr[j + 3];
            float w0 = dinv[s0], w1 = dinv[s1], w2 = dinv[s2], w3 = dinv[s3];
            a0 = fmaf(x[(size_t)s0 * 64 + f], w0, a0);
            a1 = fmaf(x[(size_t)s1 * 64 + f], w1, a1);
            a2 = fmaf(x[(size_t)s2 * 64 + f], w2, a2);
            a3 = fmaf(x[(size_t)s3 * 64 + f], w3, a3);
        }
        for (; j < je; ++j) {
            int s0 = csr[j];
            a0 = fmaf(x[(size_t)s0 * 64 + f], dinv[s0], a0);
        }
        xs[w][f] = ((a0 + a1) + (a2 + a3)) * dd;
    }
    __syncthreads();  // covers W1s/W2s staging + xs
    if (d < n) {
        float acc = b1[f];
#pragma unroll
        for (int k = 0; k < 64; ++k) acc = fmaf(xs[w][k], W1s[k * 64 + f], acc);
        vs[w][f] = fmaxf(acc, 0.0f);  // same-wave producer/consumer below
    }
    __syncthreads();
    // Phase C: each wave computes its node's 16 outputs; lane = 16*q + c.
    int q = (tid >> 4) & 3;
    int c = tid & 15;
    float p = 0.0f;
#pragma unroll
    for (int kk = 0; kk < 16; ++kk) {
        int k = q * 16 + kk;
        p = fmaf(vs[w][k], W2s[k * 16 + c], p);
    }
    p += __shfl_xor(p, 16);
    p += __shfl_xor(p, 32);
    if (q == 0 && d < n) h2[(size_t)d * 16 + c] = p;
}

// ======== Layer-2 aggregation fused with b2 + log_softmax ========
// 4 waves/block, one node per wave; lane = 16*q + c. q strides edges (2-way unrolled).

__global__ void k_agg2_lsm(const float* __restrict__ h2, const int* __restrict__ off,
                           const int* __restrict__ csr, const float* __restrict__ dinv,
                           const float* __restrict__ b2, float* __restrict__ y, int n) {
    int tid = threadIdx.x;
    int w = tid >> 6;
    int lane = tid & 63;
    int q = lane >> 4;
    int c = lane & 15;
    int d = blockIdx.x * 4 + w;
    if (d >= n) return;
    float dd = dinv[d];
    float acc0 = (q == 0) ? h2[(size_t)d * 16 + c] * dd : 0.0f;  // self-loop term
    float acc1 = 0.0f;
    int je = off[d + 1];
    int j = off[d] + q;
    for (; j + 4 < je; j += 8) {
        int s0 = csr[j], s1 = csr[j + 4];
        acc0 = fmaf(h2[(size_t)s0 * 16 + c], dinv[s0], acc0);
        acc1 = fmaf(h2[(size_t)s1 * 16 + c], dinv[s1], acc1);
    }
    if (j < je) {
        int s0 = csr[j];
        acc0 = fmaf(h2[(size_t)s0 * 16 + c], dinv[s0], acc0);
    }
    float acc = acc0 + acc1;
    acc += __shfl_xor(acc, 16);
    acc += __shfl_xor(acc, 32);
    float v = acc * dd + b2[c];
    // log_softmax across the 16 features (replicated in each q group)
    float m = v;
#pragma unroll
    for (int o = 1; o < 16; o <<= 1) m = fmaxf(m, __shfl_xor(m, o));
    float ssum = expf(v - m);
#pragma unroll
    for (int o = 1; o < 16; o <<= 1) ssum += __shfl_xor(ssum, o);
    float r = v - (logf(ssum) + m);
    if (q == 0) y[(size_t)d * 16 + c] = r;
}

// ================= launcher =================

extern "C" void kernel_launch(void* const* d_in, const int* in_sizes, int n_in,
                              void* d_out, int out_size, void* d_ws, size_t ws_size,
                              hipStream_t stream) {
    const float* x  = (const float*)d_in[0];
    const int*   ei = (const int*)d_in[1];          // [2, E] row-major
    const float* W1 = (const float*)d_in[2];
    const float* b1 = (const float*)d_in[3];
    const float* W2 = (const float*)d_in[4];
    const float* b2 = (const float*)d_in[5];
    float* y = (float*)d_out;

    const int n = N_NODES;
    const int e = N_EDGES;
    const int* src = ei;
    const int* dst = ei + e;

    // workspace layout (4-byte units); total ~10 MB
    float* ws = (float*)d_ws;
    int*   cnt    = (int*)ws;                       // n
    float* dinv   = ws + 102400;                    // n
    int*   off    = (int*)(ws + 204800);            // n+1
    int*   cursor = (int*)(ws + 307200);            // n
    int*   bsums  = (int*)(ws + 409600);            // <=1024
    int*   csr    = (int*)(ws + 410624);            // e
    float* h2     = (float*)(csr + e);              // n*16

    const int nb = (n + 1023) / 1024;               // 98 scan blocks (<=128)

    k_zero <<<(n + 255) / 256, 256, 0, stream>>>(cnt, n);
    k_count<<<(e + 255) / 256, 256, 0, stream>>>(dst, cnt, e);
    k_scanA<<<nb, 256, 0, stream>>>(cnt, off, bsums, dinv, n);
    k_scanB<<<1, 128, 0, stream>>>(bsums, off, nb, n);
    k_scanC<<<(n + 255) / 256, 256, 0, stream>>>(off, cursor, bsums, n);
    k_fill <<<(e + 255) / 256, 256, 0, stream>>>(src, dst, cursor, csr, e);

    k_agg1_fused<<<(n + 3) / 4, 256, 0, stream>>>(x, off, csr, dinv, W1, W2, b1, h2, n);
    k_agg2_lsm  <<<(n + 3) / 4, 256, 0, stream>>>(h2, off, csr, dinv, b2, y, n);
}